// Round 12
// baseline (257.214 us; speedup 1.0000x reference)
//
#include <hip/hip_runtime.h>

// NCC loss, fused single pass. R12 = R11 machinery at ~6 blocks/CU:
//  (1) 1-plane supersteps -> LDS 18.2 KB (8 blocks/CU by LDS); bank regs halved
//  (2) ZC=20, grid 1920 (=8x240 bijective XCD chunks; tile z-column ~1.5MB L2-fit)
//  (3) algebraic D epilogue: cross=IJ-uI*Js, Iv=I2-uI*Is, Jv=J2-uJ*Js (exact)
//  (4) keep: XCD swizzle, hsum XOR swizzle, VSTR=24, 8-out field-fused BSTW,
//      2-barrier superstep, lgkmcnt-only fences, bank consume-then-refill
// Volume [B=2][1][D=160][H=192][W=160] fp32. Window 9^3, zero-padded, /729.
// Tile TH=16 x TW=16, ZC=20 planes/chunk (NSTEP=28 planes touched).
// Superstep s (plane s):
//   P1: C(s): H-axis 9-tap hsum->vsum                       | barrier
//   P2: BSTW(s+1) consume bank -> hsum; ISSUE(s+2) refill; D(s) | barrier
// Hazards (single-buffered): hsum w P2(s) -> r P1(s+1): 1 bar; C r -> BSTW w:
// 1 bar (WAR); vsum w P1(s) -> r P2(s): 1 bar; D r -> C(s+1) w: 1 bar (WAR).

#define NB 2
#define ND 160
#define NH 192
#define NW 160
#define TH 16
#define TW 16
#define ZC 20
#define NSTEP (ZC + 8)      // 28 planes per chunk
#define NITER 36            // 4 blocks of 9 (static ring slots)
#define NGRID 1920          // 120 tiles x 8 zchunks x 2 batches
#define CPX (NGRID / 8)     // 240 blocks per XCD chunk
#define HROWS 25            // 24 used + pad
#define HSTR 20             // 16 used + 4
#define VROWS 17
#define VSTR 24             // D reads: 2 lanes/bank (free per m136)
#define VFSTR (VROWS * VSTR)
#define NTH 256

// XOR swizzle on hsum float4 col-base (bits 2-3) by row octave.
#define HSWZ(r) ((((r) >> 3) & 3) << 2)

__device__ __forceinline__ float4 f4add(float4 a, float4 b) {
    return make_float4(a.x + b.x, a.y + b.y, a.z + b.z, a.w + b.w);
}
__device__ __forceinline__ float4 f4sub(float4 a, float4 b) {
    return make_float4(a.x - b.x, a.y - b.y, a.z - b.z, a.w - b.w);
}

// Publish fence: drain own LDS writes, raw barrier. No vmcnt drain.
__device__ __forceinline__ void barw() {
    asm volatile("s_waitcnt lgkmcnt(0)" ::: "memory");
    __builtin_amdgcn_s_barrier();
    asm volatile("" ::: "memory");
}

__global__ __launch_bounds__(NTH) void ncc_main(
        const float* __restrict__ I, const float* __restrict__ J,
        double* __restrict__ gacc) {
    __shared__ float hsum[5][HROWS][HSTR];   // 10.0 KB
    __shared__ float vsum[5][VROWS][VSTR];   // 8.2 KB   total 18.2 KB
    __shared__ double wred[4];

    const int tid = threadIdx.x;
    const int tx = tid & 15;
    const int ty = tid >> 4;           // 0..15

    // ---- XCD-aware chunked swizzle (bijective: NGRID % 8 == 0) ----
    const int bid = blockIdx.x;
    const int nid = (bid & 7) * CPX + (bid >> 3);
    const int tile = nid >> 4;          // 16 consecutive nids = tile's (zc,b)
    const int rem = nid & 15;
    const int zci = rem >> 1;           // 0..7
    const int bb = rem & 1;
    const int tileW = tile % 10;
    const int tileH = tile / 10;
    const int w0 = tileW * TW;
    const int h0 = tileH * TH;
    const int z0 = zci * ZC;
    const size_t volBase = (size_t)bb * ND * NH * NW;

    // ---- BSTW/ISSUE decode: 48 threads = 24 halo rows x 2 octs ----
    const bool bs_on = (tid < 48);
    const int br = tid >> 1;            // 0..23 halo row
    const int bo = tid & 1;             // oct: outputs 8bo..8bo+7
    const int bh = h0 - 4 + br;
    const bool h_ok = bs_on && bh >= 0 && bh < NH;
    bool wok[4];
    int goff[4];
#pragma unroll
    for (int kk = 0; kk < 4; ++kk) {
        const int w = w0 - 4 + 8 * bo + 4 * kk;   // window cols 8bo-4..8bo+11
        wok[kk] = (w >= 0) && (w <= NW - 4);
        goff[kk] = bh * NW + w;
    }
    // register bank: 16-col raw window, both fields (consumed in place)
    float bI[16], bJ[16];
#pragma unroll
    for (int k = 0; k < 4; ++k) {
        *(float4*)&bI[4 * k] = make_float4(0.f, 0.f, 0.f, 0.f);
        *(float4*)&bJ[4 * k] = make_float4(0.f, 0.f, 0.f, 0.f);
    }

    // ---- C decode: tid 96..175 = 5f x 4 colgrp x 4 strips ----
    const bool c_on = (tid >= 96) && (tid < 176);
    const int cix = c_on ? (tid - 96) : 0;   // 0..79
    const int cf = cix >> 4;
    const int cstrip = (cix >> 2) & 3;
    const int ccg = cix & 3;
    const int cr0 = cstrip << 2;
    const int cc0 = ccg << 2;
    float* cdst = &vsum[cf][cr0][cc0];

// issue 8 global float4 loads (4 I + 4 J) for plane t (no wait)
#define ISSUE(t) do {                                                          \
    const int zt_ = z0 - 4 + (t);                                              \
    const bool zok_ = (zt_ >= 0) && (zt_ < ND);                                \
    const size_t zb_ = volBase + (size_t)zt_ * (NH * NW);                      \
    _Pragma("unroll") for (int kk = 0; kk < 4; ++kk) {                         \
        *(float4*)&bI[4 * kk] = make_float4(0.f, 0.f, 0.f, 0.f);               \
        *(float4*)&bJ[4 * kk] = make_float4(0.f, 0.f, 0.f, 0.f);               \
        if (h_ok && zok_ && wok[kk]) {                                         \
            *(float4*)&bI[4 * kk] = *(const float4*)(I + zb_ + goff[kk]);      \
            *(float4*)&bJ[4 * kk] = *(const float4*)(J + zb_ + goff[kk]);      \
        }                                                                      \
    }                                                                          \
} while (0)

// sliding 9-sum over 16-value window -> 8 outputs, write hsum (swizzled cols)
#define BSLIDE(EXPR, F) do {                                                   \
    float s_ = EXPR(0);                                                        \
    _Pragma("unroll") for (int k_ = 1; k_ < 9; ++k_) s_ += EXPR(k_);           \
    float o_[8]; o_[0] = s_;                                                   \
    _Pragma("unroll") for (int j_ = 1; j_ < 8; ++j_) {                         \
        s_ += EXPR(j_ + 8) - EXPR(j_ - 1); o_[j_] = s_; }                      \
    *(float4*)&hsum[F][br][(8 * bo) ^ HSWZ(br)]     = *(float4*)&o_[0];        \
    *(float4*)&hsum[F][br][(8 * bo + 4) ^ HSWZ(br)] = *(float4*)&o_[4];        \
} while (0)
#define E_I(k)  bI[k]
#define E_J(k)  bJ[k]
#define E_I2(k) (bI[k] * bI[k])
#define E_J2(k) (bJ[k] * bJ[k])
#define E_IJ(k) (bI[k] * bJ[k])

// consume bank: products + W-axis sliding sums -> hsum (5 fields, 8 outputs)
#define BSTW() do { if (bs_on) {                                               \
    BSLIDE(E_I, 0); BSLIDE(E_J, 1); BSLIDE(E_I2, 2);                           \
    BSLIDE(E_J2, 3); BSLIDE(E_IJ, 4);                                          \
} } while (0)

// swizzled hsum read: row r, col-quad base cc0
#define CRD(r) (*(const float4*)&hsum[cf][r][cc0 ^ HSWZ(r)])

// H-axis 9-tap sliding sums: 4-row strip, hsum -> vsum
#define DO_C() do { if (c_on) {                                                \
    float4 r0v = CRD(cr0 + 0);                                                 \
    float4 r1v = CRD(cr0 + 1);                                                 \
    float4 r2v = CRD(cr0 + 2);                                                 \
    float4 s4 = f4add(f4add(r0v, r1v), r2v);                                   \
    _Pragma("unroll") for (int k = 3; k < 9; ++k)                              \
        s4 = f4add(s4, CRD(cr0 + k));                                          \
    *(float4*)(cdst + 0 * VSTR) = s4;                                          \
    s4 = f4sub(f4add(s4, CRD(cr0 +  9)), r0v);                                 \
    *(float4*)(cdst + 1 * VSTR) = s4;                                          \
    s4 = f4sub(f4add(s4, CRD(cr0 + 10)), r1v);                                 \
    *(float4*)(cdst + 2 * VSTR) = s4;                                          \
    s4 = f4sub(f4add(s4, CRD(cr0 + 11)), r2v);                                 \
    *(float4*)(cdst + 3 * VSTR) = s4;                                          \
} } while (0)

// D: z-ring + cc epilogue (algebraically reduced: cross = IJ - uI*Js,
// Iv = I2 - uI*Is, Jv = J2 - uJ*Js -- exact identity of the reference)
#define DO_D(SLOT, IDX) do {                                                   \
    const float* vbase_ = &vsum[0][ty][tx];                                    \
    _Pragma("unroll") for (int f = 0; f < 5; ++f) {                            \
        const float v = vbase_[f * VFSTR];                                     \
        acc[f] += v - ring[f][SLOT];                                           \
        ring[f][SLOT] = v;                                                     \
    }                                                                          \
    if ((IDX) >= 8) {                                                          \
        const float Is = acc[0], Js = acc[1];                                  \
        const float I2 = acc[2], J2 = acc[3], IJ = acc[4];                     \
        const float inv = 1.0f / 729.0f;                                       \
        const float uI = Is * inv, uJ = Js * inv;                              \
        const float cross = IJ - uI * Js;                                      \
        const float Iv = I2 - uI * Is;                                         \
        const float Jv = J2 - uJ * Js;                                         \
        partial += cross * cross / (Iv * Jv + 1e-5f);                          \
    }                                                                          \
} while (0)

    float ring[5][9];
    float acc[5];
#pragma unroll
    for (int f = 0; f < 5; ++f) {
        acc[f] = 0.f;
#pragma unroll
        for (int k = 0; k < 9; ++k) ring[f][k] = 0.f;
    }
    float partial = 0.f;

    // ---- prologue: plane 0 staged into hsum; bank refilled for plane 1 ----
    ISSUE(0);
    BSTW();          // waits vmcnt for ISSUE(0) loads (once)
    ISSUE(1);
    barw();

#pragma unroll 1
    for (int ss = 0; ss < NITER; ss += 9) {
#pragma unroll
        for (int jj = 0; jj < 9; ++jj) {
            const int s = ss + jj;        // s % 9 == jj (static ring slot)
            if (s < NSTEP) {
                // ---- P1: C(s) ----
                DO_C();
                barw();

                // ---- P2: BSTW(s+1) <- bank ; ISSUE(s+2) -> bank ; D(s) ----
                if (s + 1 < NSTEP) BSTW();
                if (s + 2 < NSTEP) ISSUE(s + 2);
                DO_D(jj, s);
                barw();
            }
        }
    }

    // ---------- reduction: wave shfl -> LDS -> one atomic per block ----------
    double dp = (double)partial;
#pragma unroll
    for (int off = 32; off > 0; off >>= 1)
        dp += __shfl_down(dp, off, 64);
    if ((tid & 63) == 0) wred[tid >> 6] = dp;
    __syncthreads();
    if (tid == 0) atomicAdd(gacc, wred[0] + wred[1] + wred[2] + wred[3]);
}

__global__ void ncc_fin(const double* __restrict__ gacc, float* __restrict__ out) {
    out[0] = (float)(-gacc[0] / (double)((long long)NB * ND * NH * NW));
}

extern "C" void kernel_launch(void* const* d_in, const int* in_sizes, int n_in,
                              void* d_out, int out_size, void* d_ws, size_t ws_size,
                              hipStream_t stream) {
    const float* I = (const float*)d_in[0];   // y_true
    const float* J = (const float*)d_in[1];   // y_pred
    double* ws = (double*)d_ws;

    hipMemsetAsync(d_ws, 0, sizeof(double), stream);   // graph-capture safe

    ncc_main<<<dim3(NGRID), NTH, 0, stream>>>(I, J, ws);   // 1D swizzled grid
    ncc_fin<<<1, 1, 0, stream>>>(ws, (float*)d_out);
}

// Round 13
// 145.058 us; speedup vs baseline: 1.7732x; 1.7732x over previous
//
#include <hip/hip_runtime.h>

// NCC loss, fused single pass. R13: wave-BALANCED roles (R11 was phase-straggler
// serialized: wave0 ran all of BSTW while waves1-3 parked; VALU and LDS pipes
// summed instead of overlapped).
//  - BSTW field-split: 240 row-tasks (2pl x 5f x 24rows), one per lane (<60),
//    uniform branchless stream; decode brow=tk%24 -> HSWZ-friendly writes
//  - field4 = S((I+J)^2); D reconstructs IJ=(K2-I2-J2)/2 -> bank stays 24 regs
//  - C spread as lanes<40 of EVERY wave (160 tasks)
//  - keep: ZC=32, grid 1200 XCD-chunked, 2-barrier superstep, HSWZ, VSTR=24,
//    lgkmcnt-only fences, register consume-then-refill prefetch
// Volume [B=2][1][D=160][H=192][W=160] fp32. Window 9^3, zero-padded, /729.
// Superstep s (planes 2s,2s+1): P1: C(s) | bar; P2: BSTW(s+1); ISSUE(s+2); D(s) | bar

#define NB 2
#define ND 160
#define NH 192
#define NW 160
#define TH 16
#define TW 16
#define ZC 32
#define NSTEP (ZC + 8)      // 40 planes per chunk
#define NSUP (NSTEP / 2)    // 20 supersteps
#define NITER 27            // 3 blocks of 9 (static ring slots)
#define NGRID 1200          // 120 tiles x 5 zchunks x 2 batches
#define CPX (NGRID / 8)
#define HROWS 25
#define HSTR 20
#define VROWS 17
#define VSTR 24
#define VFSTR (VROWS * VSTR)
#define NTH 256

#define HSWZ(r) ((((r) >> 3) & 3) << 2)

__device__ __forceinline__ float4 f4add(float4 a, float4 b) {
    return make_float4(a.x + b.x, a.y + b.y, a.z + b.z, a.w + b.w);
}
__device__ __forceinline__ float4 f4sub(float4 a, float4 b) {
    return make_float4(a.x - b.x, a.y - b.y, a.z - b.z, a.w - b.w);
}

// Publish fence: drain own LDS writes, raw barrier. No vmcnt drain.
__device__ __forceinline__ void barw() {
    asm volatile("s_waitcnt lgkmcnt(0)" ::: "memory");
    __builtin_amdgcn_s_barrier();
    asm volatile("" ::: "memory");
}

__global__ __launch_bounds__(NTH) void ncc_main(
        const float* __restrict__ I, const float* __restrict__ J,
        double* __restrict__ gacc) {
    __shared__ float hsum[2][5][HROWS][HSTR];   // 20.0 KB
    __shared__ float vsum[2][5][VROWS][VSTR];   // 16.3 KB  total 36.4 KB
    __shared__ double wred[4];

    const int tid = threadIdx.x;
    const int lane = tid & 63;
    const int wv = tid >> 6;
    const int tx = tid & 15;
    const int ty = tid >> 4;

    // ---- XCD-aware chunked swizzle (bijective: NGRID % 8 == 0) ----
    const int bid = blockIdx.x;
    const int nid = (bid & 7) * CPX + (bid >> 3);
    const int tile = nid / 10;
    const int rem = nid - tile * 10;
    const int zci = rem >> 1;           // 0..4
    const int bb = rem & 1;
    const int tileW = tile % 10;
    const int tileH = tile / 10;
    const int w0 = tileW * TW;
    const int h0 = tileH * TH;
    const int z0 = zci * ZC;
    const size_t volBase = (size_t)bb * ND * NH * NW;

    // ---- BSTW/ISSUE decode: 240 tasks spread over ALL waves (lanes < 60) ----
    //      tk -> (bpl, bf, brow) with same-field rows lane-consecutive.
    const bool bs_on = (lane < 60);
    const int tk = wv * 60 + (bs_on ? lane : 0);   // 0..239
    const int bpl = tk / 120;            // plane parity within superstep
    const int bf = (tk / 24) % 5;        // field: I, J, I2, J2, K2=(I+J)^2
    const int brow = tk % 24;            // halo row
    const int bh = h0 - 4 + brow;
    const bool h_ok = bs_on && bh >= 0 && bh < NH;
    const bool isK = (bf == 4);
    const float* PA = (bf == 1 || bf == 3) ? J : I;   // primary array
    bool wok[6];
    int goff[6];
#pragma unroll
    for (int kk = 0; kk < 6; ++kk) {
        const int w = w0 - 4 + 4 * kk;   // window cols w0-4 .. w0+19
        wok[kk] = (w >= 0) && (w <= NW - 4);
        goff[kk] = bh * NW + w;
    }
    float bR[24];                        // register bank (K task: I+J summed)
#pragma unroll
    for (int k = 0; k < 6; ++k) *(float4*)&bR[4 * k] = make_float4(0.f, 0.f, 0.f, 0.f);

    // ---- C decode: 160 tasks as lanes<40 of every wave ----
    const bool c_on = (lane < 40);
    const int cix = wv * 40 + (c_on ? lane : 0);   // 0..159
    const int cpl = (cix >= 80) ? 1 : 0;
    const int c2 = cix - cpl * 80;
    const int cf = c2 >> 4;
    const int cstrip = (c2 >> 2) & 3;
    const int ccg = c2 & 3;
    const int cr0 = cstrip << 2;
    const int cc0 = ccg << 2;
    float* cdst = &vsum[cpl][cf][cr0][cc0];

// issue 6 global float4 loads for superstep t (K tasks: +6 J loads, summed)
#define ISSUE(t) do {                                                          \
    const int zt_ = z0 - 4 + 2 * (t) + bpl;                                    \
    const bool zok_ = (zt_ >= 0) && (zt_ < ND);                                \
    const size_t zb_ = volBase + (size_t)zt_ * (NH * NW);                      \
    _Pragma("unroll") for (int kk = 0; kk < 6; ++kk) {                         \
        float4 q = make_float4(0.f, 0.f, 0.f, 0.f);                            \
        if (h_ok && zok_ && wok[kk]) {                                         \
            q = *(const float4*)(PA + zb_ + goff[kk]);                         \
            if (isK) {                                                         \
                float4 q2 = *(const float4*)(J + zb_ + goff[kk]);              \
                q = f4add(q, q2);                                              \
            }                                                                  \
        }                                                                      \
        *(float4*)&bR[4 * kk] = q;                                             \
    }                                                                          \
} while (0)

// consume bank: uniform branchless product + W-axis 9-tap -> 16 outputs
#define BSTW() do { if (bs_on) {                                               \
    float p[24];                                                               \
    _Pragma("unroll") for (int k = 0; k < 24; ++k) {                           \
        const float m = (bf < 2) ? 1.0f : bR[k];                               \
        p[k] = bR[k] * m;                                                      \
    }                                                                          \
    float s = p[0];                                                            \
    _Pragma("unroll") for (int k = 1; k < 9; ++k) s += p[k];                   \
    float* hrow = &hsum[bpl][bf][brow][0];                                     \
    _Pragma("unroll") for (int g = 0; g < 4; ++g) {                            \
        float4 ov; ov.x = s;                                                   \
        s += p[g * 4 + 9]  - p[g * 4 + 0]; ov.y = s;                           \
        s += p[g * 4 + 10] - p[g * 4 + 1]; ov.z = s;                           \
        s += p[g * 4 + 11] - p[g * 4 + 2]; ov.w = s;                           \
        *(float4*)(hrow + ((4 * g) ^ HSWZ(brow))) = ov;                        \
        if (g < 3) s += p[g * 4 + 12] - p[g * 4 + 3];                          \
    }                                                                          \
} } while (0)

// swizzled hsum read: row r, col-quad base cc0
#define CRD(r) (*(const float4*)&hsum[cpl][cf][r][cc0 ^ HSWZ(r)])

// H-axis 9-tap sliding sums: 4-row strip, hsum -> vsum
#define DO_C() do { if (c_on) {                                                \
    float4 r0v = CRD(cr0 + 0);                                                 \
    float4 r1v = CRD(cr0 + 1);                                                 \
    float4 r2v = CRD(cr0 + 2);                                                 \
    float4 s4 = f4add(f4add(r0v, r1v), r2v);                                   \
    _Pragma("unroll") for (int k = 3; k < 9; ++k)                              \
        s4 = f4add(s4, CRD(cr0 + k));                                          \
    *(float4*)(cdst + 0 * VSTR) = s4;                                          \
    s4 = f4sub(f4add(s4, CRD(cr0 +  9)), r0v);                                 \
    *(float4*)(cdst + 1 * VSTR) = s4;                                          \
    s4 = f4sub(f4add(s4, CRD(cr0 + 10)), r1v);                                 \
    *(float4*)(cdst + 2 * VSTR) = s4;                                          \
    s4 = f4sub(f4add(s4, CRD(cr0 + 11)), r2v);                                 \
    *(float4*)(cdst + 3 * VSTR) = s4;                                          \
} } while (0)

// D: z-ring + cc epilogue; IJ reconstructed from K2 (linear, exact identity)
#define DO_D(PL, SLOT, IDX) do {                                               \
    const float* vbase_ = &vsum[PL][0][ty][tx];                                \
    _Pragma("unroll") for (int f = 0; f < 5; ++f) {                            \
        const float v = vbase_[f * VFSTR];                                     \
        acc[f] += v - ring[f][SLOT];                                           \
        ring[f][SLOT] = v;                                                     \
    }                                                                          \
    if ((IDX) >= 8) {                                                          \
        const float Is = acc[0], Js = acc[1];                                  \
        const float I2 = acc[2], J2 = acc[3], K2 = acc[4];                     \
        const float IJ = 0.5f * (K2 - I2 - J2);                                \
        const float inv = 1.0f / 729.0f;                                       \
        const float uI = Is * inv, uJ = Js * inv;                              \
        const float cross = IJ - uI * Js;                                      \
        const float Iv = I2 - uI * Is;                                         \
        const float Jv = J2 - uJ * Js;                                         \
        partial += cross * cross / (Iv * Jv + 1e-5f);                          \
    }                                                                          \
} while (0)

    float ring[5][9];
    float acc[5];
#pragma unroll
    for (int f = 0; f < 5; ++f) {
        acc[f] = 0.f;
#pragma unroll
        for (int k = 0; k < 9; ++k) ring[f][k] = 0.f;
    }
    float partial = 0.f;

    // ---- prologue: superstep 0 staged into hsum; bank refilled for ss 1 ----
    ISSUE(0);
    BSTW();          // compiler waits vmcnt for ISSUE(0) loads (once)
    ISSUE(1);
    barw();

#pragma unroll 1
    for (int ss = 0; ss < NITER; ss += 9) {
#pragma unroll
        for (int jj = 0; jj < 9; ++jj) {
            const int s = ss + jj;        // s % 9 == jj (static ring slots)
            if (s < NSUP) {
                // ---- P1: C(s) ----
                DO_C();
                barw();

                // ---- P2: BSTW(s+1) <- bank ; ISSUE(s+2) -> bank ; D(s) ----
                if (s + 1 < NSUP) BSTW();
                if (s + 2 < NSUP) ISSUE(s + 2);
                DO_D(0, (2 * jj) % 9, 2 * s);
                DO_D(1, (2 * jj + 1) % 9, 2 * s + 1);
                barw();
            }
        }
    }

    // ---------- reduction: wave shfl -> LDS -> one atomic per block ----------
    double dp = (double)partial;
#pragma unroll
    for (int off = 32; off > 0; off >>= 1)
        dp += __shfl_down(dp, off, 64);
    if ((tid & 63) == 0) wred[tid >> 6] = dp;
    __syncthreads();
    if (tid == 0) atomicAdd(gacc, wred[0] + wred[1] + wred[2] + wred[3]);
}

__global__ void ncc_fin(const double* __restrict__ gacc, float* __restrict__ out) {
    out[0] = (float)(-gacc[0] / (double)((long long)NB * ND * NH * NW));
}

extern "C" void kernel_launch(void* const* d_in, const int* in_sizes, int n_in,
                              void* d_out, int out_size, void* d_ws, size_t ws_size,
                              hipStream_t stream) {
    const float* I = (const float*)d_in[0];   // y_true
    const float* J = (const float*)d_in[1];   // y_pred
    double* ws = (double*)d_ws;

    hipMemsetAsync(d_ws, 0, sizeof(double), stream);   // graph-capture safe

    ncc_main<<<dim3(NGRID), NTH, 0, stream>>>(I, J, ws);   // 1D swizzled grid
    ncc_fin<<<1, 1, 0, stream>>>(ws, (float*)d_out);
}

// Round 14
// 78.788 us; speedup vs baseline: 3.2646x; 1.8411x over previous
//
#include <hip/hip_runtime.h>

// NCC loss, fused single pass. R14 = R11 (best, 91.5us) + two surgical fixes:
//  (a) BSTW 96->192 tasks WITH field fusion kept (R13 failed by splitting
//      fields across lanes -> 2.5-3x VMEM; here each lane loads its 12-col
//      window ONCE and emits all 5 fields, 4 outputs): P2 straggler 195->~150
//  (b) vsum field-interleaved [2][17][5][24]: C-write banks spread by field
//      (24f mod 32) and row (120r == 24r mod 32); D reads keep R11's free
//      2-way pattern. Kills the 13.4M C-write conflicts.
// Volume [B=2][1][D=160][H=192][W=160] fp32. Window 9^3, zero-padded, /729.
// Tile TH=16 x TW=16, ZC=32 planes/chunk (NSTEP=40 -> 20 supersteps of 2).
// Superstep s (planes 2s,2s+1):
//   P1: C(s): H-axis 9-tap hsum->vsum                      | barrier
//   P2: BSTW(s+1) consume bank -> hsum; ISSUE(s+2) refill; D(s) | barrier
// Hazards (single-buffered): hsum w P2(s)->r P1(s+1): 1 bar; C r -> BSTW w:
// 1 bar (WAR); vsum w P1(s)->r P2(s): 1 bar; D r -> C(s+1) w: 1 bar (WAR).

#define NB 2
#define ND 160
#define NH 192
#define NW 160
#define TH 16
#define TW 16
#define ZC 32
#define NSTEP (ZC + 8)      // 40 planes per chunk
#define NSUP (NSTEP / 2)    // 20 supersteps
#define NITER 27            // 3 blocks of 9 (static ring slots)
#define NGRID 1200          // 120 tiles x 5 zchunks x 2 batches
#define CPX (NGRID / 8)
#define HROWS 25
#define HSTR 20
#define VROWS 17
#define VSTR 24
#define VRSTR (5 * VSTR)    // vsum row stride = 120 words (==24 mod 32)
#define NTH 256

#define HSWZ(r) ((((r) >> 3) & 3) << 2)

__device__ __forceinline__ float4 f4add(float4 a, float4 b) {
    return make_float4(a.x + b.x, a.y + b.y, a.z + b.z, a.w + b.w);
}
__device__ __forceinline__ float4 f4sub(float4 a, float4 b) {
    return make_float4(a.x - b.x, a.y - b.y, a.z - b.z, a.w - b.w);
}

// Publish fence: drain own LDS writes, raw barrier. No vmcnt drain.
__device__ __forceinline__ void barw() {
    asm volatile("s_waitcnt lgkmcnt(0)" ::: "memory");
    __builtin_amdgcn_s_barrier();
    asm volatile("" ::: "memory");
}

__global__ __launch_bounds__(NTH) void ncc_main(
        const float* __restrict__ I, const float* __restrict__ J,
        double* __restrict__ gacc) {
    __shared__ float hsum[2][5][HROWS][HSTR];      // 20.0 KB
    __shared__ float vsum[2][VROWS][5][VSTR];      // 16.3 KB  total 36.3 KB
    __shared__ double wred[4];

    const int tid = threadIdx.x;
    const int tx = tid & 15;
    const int ty = tid >> 4;

    // ---- XCD-aware chunked swizzle (bijective: NGRID % 8 == 0) ----
    const int bid = blockIdx.x;
    const int nid = (bid & 7) * CPX + (bid >> 3);
    const int tile = nid / 10;
    const int rem = nid - tile * 10;
    const int zci = rem >> 1;           // 0..4
    const int bb = rem & 1;
    const int tileW = tile % 10;
    const int tileH = tile / 10;
    const int w0 = tileW * TW;
    const int h0 = tileH * TH;
    const int z0 = zci * ZC;
    const size_t volBase = (size_t)bb * ND * NH * NW;

    // ---- BSTW/ISSUE decode: 192 tasks = 2 planes x 24 rows x 4 col-quads,
    //      ALL-FIELD FUSED per lane (12-col window, 4 outputs x 5 fields) ----
    const bool bs_on = (tid < 192);
    const int bpl = (bs_on && tid >= 96) ? 1 : 0;
    const int b2 = bs_on ? (tid - bpl * 96) : 0;
    const int br = b2 >> 2;             // 0..23 halo row
    const int bq = b2 & 3;              // quad: outputs 4bq..4bq+3
    const int bh = h0 - 4 + br;
    const bool h_ok = bs_on && bh >= 0 && bh < NH;
    bool wok[3];
    int goff[3];
#pragma unroll
    for (int kk = 0; kk < 3; ++kk) {
        const int w = w0 - 4 + 4 * bq + 4 * kk;   // window cols 4bq-4..4bq+7
        wok[kk] = (w >= 0) && (w <= NW - 4);
        goff[kk] = bh * NW + w;
    }
    // register bank: 12-col raw window, both fields (consumed in place)
    float bI[12], bJ[12];
#pragma unroll
    for (int k = 0; k < 3; ++k) {
        *(float4*)&bI[4 * k] = make_float4(0.f, 0.f, 0.f, 0.f);
        *(float4*)&bJ[4 * k] = make_float4(0.f, 0.f, 0.f, 0.f);
    }

    // ---- C decode: tid 96..255 = 2 planes x (5f x 4 colgrp x 4 strips) ----
    const bool c_on = (tid >= 96);
    const int cix = c_on ? (tid - 96) : 0;   // 0..159
    const int cpl = (cix >= 80) ? 1 : 0;
    const int c2 = cix - cpl * 80;
    const int cf = c2 >> 4;
    const int cstrip = (c2 >> 2) & 3;
    const int ccg = c2 & 3;
    const int cr0 = cstrip << 2;
    const int cc0 = ccg << 2;
    float* cdst = &vsum[cpl][cr0][cf][cc0];

// issue 6 global float4 loads (3 I + 3 J) for superstep t, plane bpl (no wait)
#define ISSUE(t) do {                                                          \
    const int zt_ = z0 - 4 + 2 * (t) + bpl;                                    \
    const bool zok_ = (zt_ >= 0) && (zt_ < ND);                                \
    const size_t zb_ = volBase + (size_t)zt_ * (NH * NW);                      \
    _Pragma("unroll") for (int kk = 0; kk < 3; ++kk) {                         \
        *(float4*)&bI[4 * kk] = make_float4(0.f, 0.f, 0.f, 0.f);               \
        *(float4*)&bJ[4 * kk] = make_float4(0.f, 0.f, 0.f, 0.f);               \
        if (h_ok && zok_ && wok[kk]) {                                         \
            *(float4*)&bI[4 * kk] = *(const float4*)(I + zb_ + goff[kk]);      \
            *(float4*)&bJ[4 * kk] = *(const float4*)(J + zb_ + goff[kk]);      \
        }                                                                      \
    }                                                                          \
} while (0)

// sliding 9-sum over 12-value window -> 4 outputs, write hsum (swizzled cols)
#define BSLIDE(EXPR, F) do {                                                   \
    float s_ = EXPR(0);                                                        \
    _Pragma("unroll") for (int k_ = 1; k_ < 9; ++k_) s_ += EXPR(k_);           \
    float o_[4]; o_[0] = s_;                                                   \
    _Pragma("unroll") for (int j_ = 1; j_ < 4; ++j_) {                         \
        s_ += EXPR(j_ + 8) - EXPR(j_ - 1); o_[j_] = s_; }                      \
    *(float4*)&hsum[bpl][F][br][(4 * bq) ^ HSWZ(br)] = *(float4*)&o_[0];       \
} while (0)
#define E_I(k)  bI[k]
#define E_J(k)  bJ[k]
#define E_I2(k) (bI[k] * bI[k])
#define E_J2(k) (bJ[k] * bJ[k])
#define E_IJ(k) (bI[k] * bJ[k])

// consume bank: products + W-axis sliding sums -> hsum (5 fields, 4 outputs)
#define BSTW() do { if (bs_on) {                                               \
    BSLIDE(E_I, 0); BSLIDE(E_J, 1); BSLIDE(E_I2, 2);                           \
    BSLIDE(E_J2, 3); BSLIDE(E_IJ, 4);                                          \
} } while (0)

// swizzled hsum read: row r, col-quad base cc0
#define CRD(r) (*(const float4*)&hsum[cpl][cf][r][cc0 ^ HSWZ(r)])

// H-axis 9-tap sliding sums: 4-row strip, hsum -> vsum (field-interleaved)
#define DO_C() do { if (c_on) {                                                \
    float4 r0v = CRD(cr0 + 0);                                                 \
    float4 r1v = CRD(cr0 + 1);                                                 \
    float4 r2v = CRD(cr0 + 2);                                                 \
    float4 s4 = f4add(f4add(r0v, r1v), r2v);                                   \
    _Pragma("unroll") for (int k = 3; k < 9; ++k)                              \
        s4 = f4add(s4, CRD(cr0 + k));                                          \
    *(float4*)(cdst + 0 * VRSTR) = s4;                                         \
    s4 = f4sub(f4add(s4, CRD(cr0 +  9)), r0v);                                 \
    *(float4*)(cdst + 1 * VRSTR) = s4;                                         \
    s4 = f4sub(f4add(s4, CRD(cr0 + 10)), r1v);                                 \
    *(float4*)(cdst + 2 * VRSTR) = s4;                                         \
    s4 = f4sub(f4add(s4, CRD(cr0 + 11)), r2v);                                 \
    *(float4*)(cdst + 3 * VRSTR) = s4;                                         \
} } while (0)

// D: z-ring + cc epilogue (algebraically reduced, exact identity)
#define DO_D(PL, SLOT, IDX) do {                                               \
    const float* vbase_ = &vsum[PL][ty][0][tx];                                \
    _Pragma("unroll") for (int f = 0; f < 5; ++f) {                            \
        const float v = vbase_[f * VSTR];                                      \
        acc[f] += v - ring[f][SLOT];                                           \
        ring[f][SLOT] = v;                                                     \
    }                                                                          \
    if ((IDX) >= 8) {                                                          \
        const float Is = acc[0], Js = acc[1];                                  \
        const float I2 = acc[2], J2 = acc[3], IJ = acc[4];                     \
        const float inv = 1.0f / 729.0f;                                       \
        const float uI = Is * inv, uJ = Js * inv;                              \
        const float cross = IJ - uI * Js;                                      \
        const float Iv = I2 - uI * Is;                                         \
        const float Jv = J2 - uJ * Js;                                         \
        partial += cross * cross / (Iv * Jv + 1e-5f);                          \
    }                                                                          \
} while (0)

    float ring[5][9];
    float acc[5];
#pragma unroll
    for (int f = 0; f < 5; ++f) {
        acc[f] = 0.f;
#pragma unroll
        for (int k = 0; k < 9; ++k) ring[f][k] = 0.f;
    }
    float partial = 0.f;

    // ---- prologue: superstep 0 staged into hsum; bank refilled for ss 1 ----
    ISSUE(0);
    BSTW();          // compiler waits vmcnt for ISSUE(0) loads (once)
    ISSUE(1);
    barw();

#pragma unroll 1
    for (int ss = 0; ss < NITER; ss += 9) {
#pragma unroll
        for (int jj = 0; jj < 9; ++jj) {
            const int s = ss + jj;        // (2s+p) % 9 == (2jj+p) % 9: static
            if (s < NSUP) {
                // ---- P1: C(s) ----
                DO_C();
                barw();

                // ---- P2: BSTW(s+1) <- bank ; ISSUE(s+2) -> bank ; D(s) ----
                if (s + 1 < NSUP) BSTW();
                if (s + 2 < NSUP) ISSUE(s + 2);
                DO_D(0, (2 * jj) % 9, 2 * s);
                DO_D(1, (2 * jj + 1) % 9, 2 * s + 1);
                barw();
            }
        }
    }

    // ---------- reduction: wave shfl -> LDS -> one atomic per block ----------
    double dp = (double)partial;
#pragma unroll
    for (int off = 32; off > 0; off >>= 1)
        dp += __shfl_down(dp, off, 64);
    if ((tid & 63) == 0) wred[tid >> 6] = dp;
    __syncthreads();
    if (tid == 0) atomicAdd(gacc, wred[0] + wred[1] + wred[2] + wred[3]);
}

__global__ void ncc_fin(const double* __restrict__ gacc, float* __restrict__ out) {
    out[0] = (float)(-gacc[0] / (double)((long long)NB * ND * NH * NW));
}

extern "C" void kernel_launch(void* const* d_in, const int* in_sizes, int n_in,
                              void* d_out, int out_size, void* d_ws, size_t ws_size,
                              hipStream_t stream) {
    const float* I = (const float*)d_in[0];   // y_true
    const float* J = (const float*)d_in[1];   // y_pred
    double* ws = (double*)d_ws;

    hipMemsetAsync(d_ws, 0, sizeof(double), stream);   // graph-capture safe

    ncc_main<<<dim3(NGRID), NTH, 0, stream>>>(I, J, ws);   // 1D swizzled grid
    ncc_fin<<<1, 1, 0, stream>>>(ws, (float*)d_out);
}